// Round 6
// baseline (466.002 us; speedup 1.0000x reference)
//
#include <hip/hip_runtime.h>
#include <hip/hip_bf16.h>
#include <stdint.h>

// LightAttention: out = x + gamma * softmax((x Wq^T)(x Wk^T)^T / sqrt(D)) @ x
// B=4, T=4096, D=512, fp32 in/out. bf16 MFMA pipeline (threshold is bf16-grade).

#define B_ 4
#define T_ 4096
#define D_ 512

typedef short short8 __attribute__((ext_vector_type(8)));   // 8 bf16 in 4 VGPRs
typedef float f32x4 __attribute__((ext_vector_type(4)));

__device__ __forceinline__ unsigned short f2bf(float x) {
  union { float f; unsigned u; } v; v.f = x;
  unsigned r = v.u + 0x7fffu + ((v.u >> 16) & 1u);   // RNE
  return (unsigned short)(r >> 16);
}

__device__ __forceinline__ void gload_lds16(const void* g, void* l) {
  __builtin_amdgcn_global_load_lds((const __attribute__((address_space(1))) void*)g,
                                   (__attribute__((address_space(3))) void*)l, 16, 0, 0);
}

// ---------------- kernel 1: Wq/Wk fp32 -> bf16 ----------------
__global__ __launch_bounds__(256) void cvt_w(const float* __restrict__ wq,
                                             const float* __restrict__ wk,
                                             unsigned short* __restrict__ oq,
                                             unsigned short* __restrict__ ok) {
  int i = (blockIdx.x * 256 + threadIdx.x) * 4;
  const float* s; unsigned short* d;
  if (i < 262144) { s = wq + i; d = oq + i; }
  else            { s = wk + (i - 262144); d = ok + (i - 262144); }
  float4 v = *(const float4*)s;
  ushort4 h; h.x = f2bf(v.x); h.y = f2bf(v.y); h.z = f2bf(v.z); h.w = f2bf(v.w);
  *(ushort4*)d = h;
}

// ---------------- kernel 2: x -> xb (bf16 row-major) + xT (bf16 [B][D][T]) ----------------
__global__ __launch_bounds__(256) void prep_x(const float* __restrict__ x,
                                              unsigned short* __restrict__ xb,
                                              unsigned short* __restrict__ xT) {
  __shared__ unsigned short ldsT[64][72];
  int wg = blockIdx.x;                 // 2048 = 4 * (4096/64) * (512/64)
  int b = wg >> 9;
  int rem = wg & 511;
  int tt = rem >> 3, dt = rem & 7;
  int t0 = tt * 64, d0 = dt * 64;
  int tid = threadIdx.x;
  int p = tid & 15, rw = tid >> 4;
#pragma unroll
  for (int k = 0; k < 4; ++k) {
    int tr = rw + 16 * k;
    size_t off = ((size_t)(b * 4096 + t0 + tr)) * 512 + d0 + p * 4;
    float4 v = *(const float4*)(x + off);
    ushort4 h; h.x = f2bf(v.x); h.y = f2bf(v.y); h.z = f2bf(v.z); h.w = f2bf(v.w);
    *(ushort4*)(xb + off) = h;
    ldsT[p * 4 + 0][tr] = h.x; ldsT[p * 4 + 1][tr] = h.y;
    ldsT[p * 4 + 2][tr] = h.z; ldsT[p * 4 + 3][tr] = h.w;
  }
  __syncthreads();
#pragma unroll
  for (int k = 0; k < 4; ++k) {
    int dr = rw + 16 * k;
    ushort4 h;
    h.x = ldsT[dr][p * 4 + 0]; h.y = ldsT[dr][p * 4 + 1];
    h.z = ldsT[dr][p * 4 + 2]; h.w = ldsT[dr][p * 4 + 3];
    *(ushort4*)(xT + (size_t)b * 512 * 4096 + (size_t)(d0 + dr) * 4096 + t0 + p * 4) = h;
  }
}

// ---------------- kernel 3: Q/K projection GEMM (128x128x64, bf16 MFMA) ----------------
__global__ __launch_bounds__(256, 2) void proj_gemm(const unsigned short* __restrict__ A,
                                                    const unsigned short* __restrict__ wq,
                                                    const unsigned short* __restrict__ wk,
                                                    const float* __restrict__ bq,
                                                    const float* __restrict__ bk,
                                                    unsigned short* __restrict__ Qo,
                                                    unsigned short* __restrict__ Ko,
                                                    float qscale) {
  __shared__ unsigned short As[2][8192];
  __shared__ unsigned short Bs[2][8192];
  const int tid = threadIdx.x;
  const int mt = blockIdx.x, nt = blockIdx.y, qk = blockIdx.z;
  const unsigned short* W = qk ? wk : wq;
  const float* bias = qk ? bk : bq;
  unsigned short* out = qk ? Ko : Qo;
  const float sc = qk ? 1.0f : qscale;
  const int m0 = mt * 128, n0 = nt * 128;
  const int l = tid & 63, q15 = l & 15, g = l >> 4;
  const int w = tid >> 6, wm = w >> 1, wn = w & 1;

  auto stage = [&](int buf, int k0) {
#pragma unroll
    for (int j = 0; j < 4; ++j) {
      int chunk = j * 256 + tid;
      int row = chunk >> 3, cc = chunk & 7;
      int ccs = cc ^ (row & 7);
      gload_lds16(A + (size_t)(m0 + row) * 512 + k0 + ccs * 8, &As[buf][chunk * 8]);
      gload_lds16(W + (size_t)(n0 + row) * 512 + k0 + ccs * 8, &Bs[buf][chunk * 8]);
    }
  };
  stage(0, 0);
  __syncthreads();

  f32x4 acc[4][4] = {};
  for (int kt = 0; kt < 8; ++kt) {
    int cur = kt & 1;
    if (kt < 7) stage(cur ^ 1, (kt + 1) * 64);
#pragma unroll
    for (int ks = 0; ks < 2; ++ks) {
      short8 av[4], bv[4];
#pragma unroll
      for (int mf = 0; mf < 4; ++mf) {
        int row = 64 * wm + 16 * mf + q15;
        int cb = (ks * 64 + g * 16) ^ ((row & 7) << 4);
        av[mf] = *(const short8*)((const char*)&As[cur][0] + row * 128 + cb);
      }
#pragma unroll
      for (int nf = 0; nf < 4; ++nf) {
        int row = 64 * wn + 16 * nf + q15;
        int cb = (ks * 64 + g * 16) ^ ((row & 7) << 4);
        bv[nf] = *(const short8*)((const char*)&Bs[cur][0] + row * 128 + cb);
      }
#pragma unroll
      for (int mf = 0; mf < 4; ++mf)
#pragma unroll
        for (int nf = 0; nf < 4; ++nf)
          acc[mf][nf] = __builtin_amdgcn_mfma_f32_16x16x32_bf16(av[mf], bv[nf], acc[mf][nf], 0, 0, 0);
    }
    __syncthreads();
  }
#pragma unroll
  for (int nf = 0; nf < 4; ++nf) {
    int n = n0 + 64 * wn + 16 * nf + q15;
    float bv = bias[n];
#pragma unroll
    for (int mf = 0; mf < 4; ++mf) {
      int mbase = m0 + 64 * wm + 16 * mf + 4 * g;
#pragma unroll
      for (int r = 0; r < 4; ++r)
        out[(size_t)(mbase + r) * 512 + n] = f2bf((acc[mf][nf][r] + bv) * sc);
    }
  }
}

// ---------------- kernel 4: fused flash attention + residual ----------------
// 512 WGs x 384 threads (6 waves), 32 q-rows per WG, KV tile = 32 (128 tiles).
// LDS ~71 KB -> 2 independent WGs co-resident per CU (latency hiding across WGs).
//   waves 0-1 (QK): wave w owns q 16w..16w+15. Q frags in regs; swapped
//                   mfma(K,Q) -> S^T; per-lane online softmax; writes P+scale.
//   waves 2-5 (PV): wave pw owns dout d 128pw..128pw+127, all 32 q (Oacc 64
//                   regs); consumes P/scale of PREVIOUS tile (1-slot skew);
//                   stages next K tile via global_load_lds DMA.
// All sync = __syncthreads() (one per slot).
__global__ __launch_bounds__(384, 3) void attn_kernel(const unsigned short* __restrict__ Qb,
                                                      const unsigned short* __restrict__ Kb,
                                                      const unsigned short* __restrict__ xT,
                                                      const float* __restrict__ x,
                                                      const float* __restrict__ gmp,
                                                      float* __restrict__ out) {
  extern __shared__ char smem[];
  // [0, 65536)      : Kbuf 2 x [32 rows][1024 B], XOR-swizzled 16B chunks
  // [65536, 70656)  : P    2 x [32 q][40 kv] bf16 (row stride 80 B)
  // [70656, 70912)  : scale 2 x [32] f32
  // [70912, 71040)  : lsum [32] f32
  // [71040, 71056)  : flags 2 x [2] u32 (per-QK-wave "scale==1" flag)
  char* Pbase      = smem + 65536;
  float* scale_lds = (float*)(smem + 70656);
  float* lsum_lds  = (float*)(smem + 70912);
  unsigned* flags  = (unsigned*)(smem + 71040);

  const int hw = blockIdx.x;
  const int wg = (hw & 7) * 64 + (hw >> 3);   // XCD-chunked swizzle (512 % 8 == 0)
  const int b = wg >> 7, qt = wg & 127;       // 128 q-blocks of 32 per batch
  const int tid = threadIdx.x;
  const int w = tid >> 6, l = tid & 63, q15 = l & 15, g = l >> 4;

  const unsigned short* KbB = Kb + (size_t)b * 4096 * 512;
  const unsigned short* xTb = xT + (size_t)b * 512 * 4096;

  // stage K tile kt (32 rows x 1KB = 2048 x 16B chunks) by the 4 PV waves.
  // linear LDS dest, inverse-swizzled global src: row r chunk c holds
  // K[r][(c ^ (r&7))*8 ..+8)
  auto stage = [&](int buf, int kt) {
    const unsigned short* src = KbB + (size_t)kt * 32 * 512;
    char* dst = smem + buf * 32768;
    int st = tid - 128;
#pragma unroll
    for (int j = 0; j < 8; ++j) {
      int ch = j * 256 + st;
      int r = ch >> 6, c = ch & 63;
      gload_lds16(src + (size_t)r * 512 + ((c ^ (r & 7)) << 3), dst + ch * 16);
    }
  };

  if (tid >= 128) stage(0, 0);
  __syncthreads();

  if (w < 2) {
    // ================= QK + softmax waves (16 q each) =================
    short8 qf_[16];
    {
      const unsigned short* Qrow =
          Qb + ((size_t)(b * 4096 + qt * 32 + 16 * w + q15)) * 512 + g * 8;
#pragma unroll
      for (int ds = 0; ds < 16; ++ds) qf_[ds] = *(const short8*)(Qrow + ds * 32);
    }
    float mrun = -1e30f, lsum = 0.f;

#pragma unroll 1
    for (int s = 0; s <= 128; ++s) {
      if (s < 128) {
        const int cur = s & 1;
        // QK^T (swapped): S^T[kv][q], frag kvg covers kv 16kvg..16kvg+15
        f32x4 Sacc[2] = {};
        const char* kb = smem + cur * 32768;
        __builtin_amdgcn_s_setprio(1);
#pragma unroll
        for (int ds = 0; ds < 16; ++ds) {
#pragma unroll
          for (int kvg = 0; kvg < 2; ++kvg) {
            int row = 16 * kvg + q15;
            int cb = ((4 * ds + g) ^ (row & 7)) << 4;
            short8 kf = *(const short8*)(kb + row * 1024 + cb);
            Sacc[kvg] = __builtin_amdgcn_mfma_f32_16x16x32_bf16(kf, qf_[ds], Sacc[kvg], 0, 0, 0);
          }
        }
        __builtin_amdgcn_s_setprio(0);
        // online softmax: lane owns q = 16w+q15; values kv = 16kvg + 4g + r
        float pmax = -1e30f;
#pragma unroll
        for (int kvg = 0; kvg < 2; ++kvg)
#pragma unroll
          for (int r = 0; r < 4; ++r) pmax = fmaxf(pmax, Sacc[kvg][r]);
        pmax = fmaxf(pmax, __shfl_xor(pmax, 16, 64));
        pmax = fmaxf(pmax, __shfl_xor(pmax, 32, 64));
        const float mnew = fmaxf(mrun, pmax);
        const float scl = __expf(mrun - mnew);
        float psum = 0.f;
        const int q_loc = 16 * w + q15;
        char* Pp = Pbase + cur * 2560 + q_loc * 80 + 8 * g;
#pragma unroll
        for (int kvg = 0; kvg < 2; ++kvg) {
          ushort4 pk;
          float p0 = __expf(Sacc[kvg][0] - mnew); psum += p0; pk.x = f2bf(p0);
          float p1 = __expf(Sacc[kvg][1] - mnew); psum += p1; pk.y = f2bf(p1);
          float p2 = __expf(Sacc[kvg][2] - mnew); psum += p2; pk.z = f2bf(p2);
          float p3 = __expf(Sacc[kvg][3] - mnew); psum += p3; pk.w = f2bf(p3);
          *(ushort4*)(Pp + 32 * kvg) = pk;
        }
        psum += __shfl_xor(psum, 16, 64);
        psum += __shfl_xor(psum, 32, 64);
        lsum = lsum * scl + psum;
        const bool nochg = (mnew == mrun);
        mrun = mnew;
        if (g == 0) scale_lds[cur * 32 + q_loc] = scl;
        if (s == 127 && g == 0) lsum_lds[q_loc] = lsum;
        unsigned long long bal = __ballot(nochg ? 1 : 0);
        if (l == 0) flags[cur * 2 + w] = (bal == 0xFFFFFFFFFFFFFFFFull) ? 1u : 0u;
      }
      __syncthreads();
    }
  } else {
    // ================= PV + rescale waves (32 q x 128 d each) =================
    const int pw = w - 2;
    f32x4 Oacc[2][8] = {};

#pragma unroll 1
    for (int s = 0; s <= 128; ++s) {
      if (s < 127) stage((s + 1) & 1, s + 1);
      if (s >= 1) {
        const int tv = s - 1;            // tile consumed this slot
        const int pcur = tv & 1;
        // V B-frags straight from L2 (xT row-slice, 32 kv)
        short8 vf[8];
#pragma unroll
        for (int f = 0; f < 8; ++f)
          vf[f] = *(const short8*)(xTb + (size_t)(128 * pw + 16 * f + q15) * 4096
                                   + tv * 32 + g * 8);
        const bool skip = (flags[pcur * 2 + 0] & flags[pcur * 2 + 1]) != 0;
        const float* scp = scale_lds + pcur * 32;
        const char* Pb = Pbase + pcur * 2560;
#pragma unroll
        for (int qf = 0; qf < 2; ++qf) {
          short8 pa = *(const short8*)(Pb + (16 * qf + q15) * 80 + g * 16);
          if (!skip) {
            float s0 = scp[16 * qf + 4 * g + 0];
            float s1 = scp[16 * qf + 4 * g + 1];
            float s2 = scp[16 * qf + 4 * g + 2];
            float s3 = scp[16 * qf + 4 * g + 3];
#pragma unroll
            for (int f = 0; f < 8; ++f) {
              Oacc[qf][f][0] *= s0; Oacc[qf][f][1] *= s1;
              Oacc[qf][f][2] *= s2; Oacc[qf][f][3] *= s3;
            }
          }
          __builtin_amdgcn_s_setprio(1);
#pragma unroll
          for (int f = 0; f < 8; ++f)
            Oacc[qf][f] = __builtin_amdgcn_mfma_f32_16x16x32_bf16(pa, vf[f], Oacc[qf][f], 0, 0, 0);
          __builtin_amdgcn_s_setprio(0);
        }
      }
      __syncthreads();
    }

    // epilogue: PV waves write out
    const float gam = gmp[0];
#pragma unroll
    for (int qf = 0; qf < 2; ++qf) {
      float li0 = 1.f / lsum_lds[16 * qf + 4 * g + 0];
      float li1 = 1.f / lsum_lds[16 * qf + 4 * g + 1];
      float li2 = 1.f / lsum_lds[16 * qf + 4 * g + 2];
      float li3 = 1.f / lsum_lds[16 * qf + 4 * g + 3];
#pragma unroll
      for (int f = 0; f < 8; ++f) {
        int d = 128 * pw + 16 * f + q15;
        size_t base = ((size_t)(b * 4096 + qt * 32 + 16 * qf + 4 * g)) * 512 + d;
        f32x4 a = Oacc[qf][f];
        out[base]        = x[base]        + gam * a[0] * li0;
        out[base + 512]  = x[base + 512]  + gam * a[1] * li1;
        out[base + 1024] = x[base + 1024] + gam * a[2] * li2;
        out[base + 1536] = x[base + 1536] + gam * a[3] * li3;
      }
    }
  }
}

// ---------------- launch ----------------
extern "C" void kernel_launch(void* const* d_in, const int* in_sizes, int n_in,
                              void* d_out, int out_size, void* d_ws, size_t ws_size,
                              hipStream_t stream) {
  (void)in_sizes; (void)n_in; (void)out_size; (void)ws_size;
  const float* x  = (const float*)d_in[0];
  const float* Wq = (const float*)d_in[1];
  const float* bq = (const float*)d_in[2];
  const float* Wk = (const float*)d_in[3];
  const float* bk = (const float*)d_in[4];
  const float* gm = (const float*)d_in[5];
  float* out = (float*)d_out;

  char* ws = (char*)d_ws;   // ~68.2 MB
  unsigned short* Qb  = (unsigned short*)(ws);                // 16384*512 bf16
  unsigned short* Kb  = (unsigned short*)(ws + 16777216);     // 16384*512 bf16
  unsigned short* xT  = (unsigned short*)(ws + 33554432);     // 4*512*4096 bf16
  unsigned short* xb  = (unsigned short*)(ws + 50331648);     // 16384*512 bf16
  unsigned short* Wqb = (unsigned short*)(ws + 67108864);     // 512*512 bf16
  unsigned short* Wkb = (unsigned short*)(ws + 67633152);     // 512*512 bf16

  hipFuncSetAttribute((const void*)attn_kernel,
                      hipFuncAttributeMaxDynamicSharedMemorySize, 71056);

  cvt_w<<<512, 256, 0, stream>>>(Wq, Wk, Wqb, Wkb);
  prep_x<<<2048, 256, 0, stream>>>(x, xb, xT);
  proj_gemm<<<dim3(128, 4, 2), 256, 0, stream>>>(xb, Wqb, Wkb, bq, bk, Qb, Kb,
                                                 0.04419417382415922f);
  attn_kernel<<<512, 384, 71056, stream>>>(Qb, Kb, xT, x, gm, out);
}

// Round 7
// 442.617 us; speedup vs baseline: 1.0528x; 1.0528x over previous
//
#include <hip/hip_runtime.h>
#include <hip/hip_bf16.h>
#include <stdint.h>

// LightAttention: out = x + gamma * softmax((x Wq^T)(x Wk^T)^T / sqrt(D)) @ x
// B=4, T=4096, D=512, fp32 in/out. bf16 MFMA pipeline (threshold is bf16-grade).

#define B_ 4
#define T_ 4096
#define D_ 512

typedef short short8 __attribute__((ext_vector_type(8)));   // 8 bf16 in 4 VGPRs
typedef float f32x4 __attribute__((ext_vector_type(4)));

__device__ __forceinline__ unsigned short f2bf(float x) {
  union { float f; unsigned u; } v; v.f = x;
  unsigned r = v.u + 0x7fffu + ((v.u >> 16) & 1u);   // RNE
  return (unsigned short)(r >> 16);
}

__device__ __forceinline__ void gload_lds16(const void* g, void* l) {
  __builtin_amdgcn_global_load_lds((const __attribute__((address_space(1))) void*)g,
                                   (__attribute__((address_space(3))) void*)l, 16, 0, 0);
}

// ---------------- kernel 1: Wq/Wk fp32 -> bf16 ----------------
__global__ __launch_bounds__(256) void cvt_w(const float* __restrict__ wq,
                                             const float* __restrict__ wk,
                                             unsigned short* __restrict__ oq,
                                             unsigned short* __restrict__ ok) {
  int i = (blockIdx.x * 256 + threadIdx.x) * 4;
  const float* s; unsigned short* d;
  if (i < 262144) { s = wq + i; d = oq + i; }
  else            { s = wk + (i - 262144); d = ok + (i - 262144); }
  float4 v = *(const float4*)s;
  ushort4 h; h.x = f2bf(v.x); h.y = f2bf(v.y); h.z = f2bf(v.z); h.w = f2bf(v.w);
  *(ushort4*)d = h;
}

// ---------------- kernel 2: x -> xb (bf16 row-major) + xT (bf16 [B][D][T]) ----------------
__global__ __launch_bounds__(256) void prep_x(const float* __restrict__ x,
                                              unsigned short* __restrict__ xb,
                                              unsigned short* __restrict__ xT) {
  __shared__ unsigned short ldsT[64][72];
  int wg = blockIdx.x;                 // 2048 = 4 * (4096/64) * (512/64)
  int b = wg >> 9;
  int rem = wg & 511;
  int tt = rem >> 3, dt = rem & 7;
  int t0 = tt * 64, d0 = dt * 64;
  int tid = threadIdx.x;
  int p = tid & 15, rw = tid >> 4;
#pragma unroll
  for (int k = 0; k < 4; ++k) {
    int tr = rw + 16 * k;
    size_t off = ((size_t)(b * 4096 + t0 + tr)) * 512 + d0 + p * 4;
    float4 v = *(const float4*)(x + off);
    ushort4 h; h.x = f2bf(v.x); h.y = f2bf(v.y); h.z = f2bf(v.z); h.w = f2bf(v.w);
    *(ushort4*)(xb + off) = h;
    ldsT[p * 4 + 0][tr] = h.x; ldsT[p * 4 + 1][tr] = h.y;
    ldsT[p * 4 + 2][tr] = h.z; ldsT[p * 4 + 3][tr] = h.w;
  }
  __syncthreads();
#pragma unroll
  for (int k = 0; k < 4; ++k) {
    int dr = rw + 16 * k;
    ushort4 h;
    h.x = ldsT[dr][p * 4 + 0]; h.y = ldsT[dr][p * 4 + 1];
    h.z = ldsT[dr][p * 4 + 2]; h.w = ldsT[dr][p * 4 + 3];
    *(ushort4*)(xT + (size_t)b * 512 * 4096 + (size_t)(d0 + dr) * 4096 + t0 + p * 4) = h;
  }
}

// ---------------- kernel 3: Q/K projection GEMM (128x128x64, bf16 MFMA) ----------------
__global__ __launch_bounds__(256, 2) void proj_gemm(const unsigned short* __restrict__ A,
                                                    const unsigned short* __restrict__ wq,
                                                    const unsigned short* __restrict__ wk,
                                                    const float* __restrict__ bq,
                                                    const float* __restrict__ bk,
                                                    unsigned short* __restrict__ Qo,
                                                    unsigned short* __restrict__ Ko,
                                                    float qscale) {
  __shared__ unsigned short As[2][8192];
  __shared__ unsigned short Bs[2][8192];
  const int tid = threadIdx.x;
  const int mt = blockIdx.x, nt = blockIdx.y, qk = blockIdx.z;
  const unsigned short* W = qk ? wk : wq;
  const float* bias = qk ? bk : bq;
  unsigned short* out = qk ? Ko : Qo;
  const float sc = qk ? 1.0f : qscale;
  const int m0 = mt * 128, n0 = nt * 128;
  const int l = tid & 63, q15 = l & 15, g = l >> 4;
  const int w = tid >> 6, wm = w >> 1, wn = w & 1;

  auto stage = [&](int buf, int k0) {
#pragma unroll
    for (int j = 0; j < 4; ++j) {
      int chunk = j * 256 + tid;
      int row = chunk >> 3, cc = chunk & 7;
      int ccs = cc ^ (row & 7);
      gload_lds16(A + (size_t)(m0 + row) * 512 + k0 + ccs * 8, &As[buf][chunk * 8]);
      gload_lds16(W + (size_t)(n0 + row) * 512 + k0 + ccs * 8, &Bs[buf][chunk * 8]);
    }
  };
  stage(0, 0);
  __syncthreads();

  f32x4 acc[4][4] = {};
  for (int kt = 0; kt < 8; ++kt) {
    int cur = kt & 1;
    if (kt < 7) stage(cur ^ 1, (kt + 1) * 64);
#pragma unroll
    for (int ks = 0; ks < 2; ++ks) {
      short8 av[4], bv[4];
#pragma unroll
      for (int mf = 0; mf < 4; ++mf) {
        int row = 64 * wm + 16 * mf + q15;
        int cb = (ks * 64 + g * 16) ^ ((row & 7) << 4);
        av[mf] = *(const short8*)((const char*)&As[cur][0] + row * 128 + cb);
      }
#pragma unroll
      for (int nf = 0; nf < 4; ++nf) {
        int row = 64 * wn + 16 * nf + q15;
        int cb = (ks * 64 + g * 16) ^ ((row & 7) << 4);
        bv[nf] = *(const short8*)((const char*)&Bs[cur][0] + row * 128 + cb);
      }
#pragma unroll
      for (int mf = 0; mf < 4; ++mf)
#pragma unroll
        for (int nf = 0; nf < 4; ++nf)
          acc[mf][nf] = __builtin_amdgcn_mfma_f32_16x16x32_bf16(av[mf], bv[nf], acc[mf][nf], 0, 0, 0);
    }
    __syncthreads();
  }
#pragma unroll
  for (int nf = 0; nf < 4; ++nf) {
    int n = n0 + 64 * wn + 16 * nf + q15;
    float bv = bias[n];
#pragma unroll
    for (int mf = 0; mf < 4; ++mf) {
      int mbase = m0 + 64 * wm + 16 * mf + 4 * g;
#pragma unroll
      for (int r = 0; r < 4; ++r)
        out[(size_t)(mbase + r) * 512 + n] = f2bf((acc[mf][nf][r] + bv) * sc);
    }
  }
}

// ---------------- kernel 4: fused flash attention + residual ----------------
// 640 threads = 10 waves, wave-specialized, KV tile = 64, 64 tiles:
//   waves 0-1 (QK): wave w owns q 32w..32w+31 (Q frags 128 VGPR, 2 q-groups;
//                   each K fragment read once, used for 2 MFMAs). Swapped
//                   mfma(K,Q) -> S^T; per-lane online softmax (2 q per lane);
//                   writes P + scale + per-wave "no rescale" flag.
//   waves 2-9 (PV): wave pw owns dout d 64pw..64pw+63, all 64 q (Oacc 64
//                   regs); consumes P/scale of the PREVIOUS tile (1-slot
//                   skew); stages next K tile via global_load_lds DMA.
// All sync = __syncthreads() (one per slot). NO min-waves launch bound:
// QK waves need ~200 VGPRs (R4 lesson: a forced cap -> scratch spills).
__global__ __launch_bounds__(640) void attn_kernel(const unsigned short* __restrict__ Qb,
                                                   const unsigned short* __restrict__ Kb,
                                                   const unsigned short* __restrict__ xT,
                                                   const float* __restrict__ x,
                                                   const float* __restrict__ gmp,
                                                   float* __restrict__ out) {
  extern __shared__ char smem[];
  // [0, 131072)      : Kbuf 2 x [64 rows][1024 B], XOR-swizzled 16B chunks
  // [131072, 149504) : P    2 x [64 q][72 kv] bf16 (row stride 144 B)
  // [149504, 150016) : scale 2 x [64] f32
  // [150016, 150272) : lsum [64] f32
  // [150272, 150288) : flags 2 x [2] u32 (per-QK-wave "scale==1" flag)
  unsigned short* Pl = (unsigned short*)(smem + 131072);
  float* scale_lds = (float*)(smem + 149504);
  float* lsum_lds  = (float*)(smem + 150016);
  unsigned* flags  = (unsigned*)(smem + 150272);

  const int hw = blockIdx.x;
  const int wg = (hw & 7) * 32 + (hw >> 3);   // XCD-chunked swizzle (256 % 8 == 0)
  const int b = wg >> 6, qt = wg & 63;
  const int tid = threadIdx.x;
  const int w = tid >> 6, l = tid & 63, q15 = l & 15, g = l >> 4;

  const unsigned short* KbB = Kb + (size_t)b * 4096 * 512;
  const unsigned short* xTb = xT + (size_t)b * 512 * 4096;

  // stage K tile kt (64 rows x 1KB = 4096 x 16B chunks) by the 8 PV waves.
  // linear LDS dest, inverse-swizzled global src: row r chunk c holds
  // K[r][(c ^ (r&7))*8 ..+8)
  auto stage = [&](int buf, int kt) {
    const unsigned short* src = KbB + (size_t)kt * 64 * 512;
    char* dst = smem + buf * 65536;
    int st = tid - 128;
#pragma unroll
    for (int j = 0; j < 8; ++j) {
      int ch = j * 512 + st;
      int r = ch >> 6, c = ch & 63;
      gload_lds16(src + (size_t)r * 512 + ((c ^ (r & 7)) << 3), dst + ch * 16);
    }
  };

  if (tid >= 128) stage(0, 0);
  __syncthreads();

  if (w < 2) {
    // ================= QK + softmax waves (32 q each) =================
    // Q B-frags: qf_[qg][ds] covers q = qt*64+32w+16qg+q15, k = 32ds+8g..+8
    short8 qf_[2][16];
#pragma unroll
    for (int qg = 0; qg < 2; ++qg) {
      const unsigned short* Qrow =
          Qb + ((size_t)(b * 4096 + qt * 64 + 32 * w + 16 * qg + q15)) * 512 + g * 8;
#pragma unroll
      for (int ds = 0; ds < 16; ++ds) qf_[qg][ds] = *(const short8*)(Qrow + ds * 32);
    }
    float mrun0 = -1e30f, mrun1 = -1e30f, lsum0 = 0.f, lsum1 = 0.f;

#pragma unroll 1
    for (int s = 0; s <= 64; ++s) {
      if (s < 64) {
        const int cur = s & 1;
        // QK^T (swapped): S^T[kv][q]; kvg covers kv 16kvg..+15, qg the q-group.
        // Each K frag read once, used for both q-groups.
        f32x4 Sacc[4][2] = {};
        const char* kb = smem + cur * 65536;
        __builtin_amdgcn_s_setprio(1);
#pragma unroll
        for (int ds = 0; ds < 16; ++ds) {
#pragma unroll
          for (int kvg = 0; kvg < 4; ++kvg) {
            int row = 16 * kvg + q15;
            int cb = ((4 * ds + g) ^ (row & 7)) << 4;
            short8 kf = *(const short8*)(kb + row * 1024 + cb);
            Sacc[kvg][0] = __builtin_amdgcn_mfma_f32_16x16x32_bf16(kf, qf_[0][ds], Sacc[kvg][0], 0, 0, 0);
            Sacc[kvg][1] = __builtin_amdgcn_mfma_f32_16x16x32_bf16(kf, qf_[1][ds], Sacc[kvg][1], 0, 0, 0);
          }
        }
        __builtin_amdgcn_s_setprio(0);
        // online softmax: lane owns q = 32w+16qg+q15 (two q); kv = 16kvg+4g+r
        bool nochg = true;
#pragma unroll
        for (int qg = 0; qg < 2; ++qg) {
          float& mrun = qg ? mrun1 : mrun0;
          float& lsum = qg ? lsum1 : lsum0;
          float pmax = -1e30f;
#pragma unroll
          for (int kvg = 0; kvg < 4; ++kvg)
#pragma unroll
            for (int r = 0; r < 4; ++r) pmax = fmaxf(pmax, Sacc[kvg][qg][r]);
          pmax = fmaxf(pmax, __shfl_xor(pmax, 16, 64));
          pmax = fmaxf(pmax, __shfl_xor(pmax, 32, 64));
          const float mnew = fmaxf(mrun, pmax);
          nochg = nochg && (mnew == mrun);
          const float scl = __expf(mrun - mnew);
          float psum = 0.f;
          const int q_loc = 32 * w + 16 * qg + q15;
          unsigned short* Pp = Pl + cur * 4608 + q_loc * 72 + 4 * g;
#pragma unroll
          for (int kvg = 0; kvg < 4; ++kvg) {
            ushort4 pk;
            float p0 = __expf(Sacc[kvg][qg][0] - mnew); psum += p0; pk.x = f2bf(p0);
            float p1 = __expf(Sacc[kvg][qg][1] - mnew); psum += p1; pk.y = f2bf(p1);
            float p2 = __expf(Sacc[kvg][qg][2] - mnew); psum += p2; pk.z = f2bf(p2);
            float p3 = __expf(Sacc[kvg][qg][3] - mnew); psum += p3; pk.w = f2bf(p3);
            *(ushort4*)(Pp + 16 * kvg) = pk;
          }
          psum += __shfl_xor(psum, 16, 64);
          psum += __shfl_xor(psum, 32, 64);
          lsum = lsum * scl + psum;
          mrun = mnew;
          if (g == 0) scale_lds[cur * 64 + q_loc] = scl;
          if (s == 63 && g == 0) lsum_lds[q_loc] = lsum;
        }
        unsigned long long bal = __ballot(nochg ? 1 : 0);
        if (l == 0) flags[cur * 2 + w] = (bal == 0xFFFFFFFFFFFFFFFFull) ? 1u : 0u;
      }
      __syncthreads();
    }
  } else {
    // ================= PV + rescale waves (64 q x 64 d each) =================
    const int pw = w - 2;
    f32x4 Oacc[4][4] = {};

#pragma unroll 1
    for (int s = 0; s <= 64; ++s) {
      if (s < 63) stage((s + 1) & 1, s + 1);
      if (s >= 1) {
        const int tv = s - 1;            // tile consumed this slot
        const int pcur = tv & 1;
        // V B-frags straight from L2 (xT row-slice, 64 kv)
        short8 vf[4][2];
#pragma unroll
        for (int f = 0; f < 4; ++f)
#pragma unroll
          for (int ks = 0; ks < 2; ++ks)
            vf[f][ks] = *(const short8*)(xTb + (size_t)(64 * pw + 16 * f + q15) * 4096
                                         + tv * 64 + ks * 32 + g * 8);
        const bool skip = (flags[pcur * 2 + 0] & flags[pcur * 2 + 1]) != 0;
        const float* scp = scale_lds + pcur * 64;
        const char* Pb = (const char*)Pl + pcur * 9216;
#pragma unroll
        for (int qf = 0; qf < 4; ++qf) {
          const char* prow = Pb + (16 * qf + q15) * 144 + g * 16;
          short8 pa0 = *(const short8*)(prow);
          short8 pa1 = *(const short8*)(prow + 64);
          if (!skip) {
            float s0 = scp[16 * qf + 4 * g + 0];
            float s1 = scp[16 * qf + 4 * g + 1];
            float s2 = scp[16 * qf + 4 * g + 2];
            float s3 = scp[16 * qf + 4 * g + 3];
#pragma unroll
            for (int f = 0; f < 4; ++f) {
              Oacc[qf][f][0] *= s0; Oacc[qf][f][1] *= s1;
              Oacc[qf][f][2] *= s2; Oacc[qf][f][3] *= s3;
            }
          }
          __builtin_amdgcn_s_setprio(1);
#pragma unroll
          for (int f = 0; f < 4; ++f) {
            f32x4 a = Oacc[qf][f];
            a = __builtin_amdgcn_mfma_f32_16x16x32_bf16(pa0, vf[f][0], a, 0, 0, 0);
            a = __builtin_amdgcn_mfma_f32_16x16x32_bf16(pa1, vf[f][1], a, 0, 0, 0);
            Oacc[qf][f] = a;
          }
          __builtin_amdgcn_s_setprio(0);
        }
      }
      __syncthreads();
    }

    // epilogue: PV waves write out
    const float gam = gmp[0];
#pragma unroll
    for (int qf = 0; qf < 4; ++qf) {
      float li0 = 1.f / lsum_lds[16 * qf + 4 * g + 0];
      float li1 = 1.f / lsum_lds[16 * qf + 4 * g + 1];
      float li2 = 1.f / lsum_lds[16 * qf + 4 * g + 2];
      float li3 = 1.f / lsum_lds[16 * qf + 4 * g + 3];
#pragma unroll
    for (int f = 0; f < 4; ++f) {
        int d = 64 * pw + 16 * f + q15;
        size_t base = ((size_t)(b * 4096 + qt * 64 + 16 * qf + 4 * g)) * 512 + d;
        f32x4 a = Oacc[qf][f];
        out[base]        = x[base]        + gam * a[0] * li0;
        out[base + 512]  = x[base + 512]  + gam * a[1] * li1;
        out[base + 1024] = x[base + 1024] + gam * a[2] * li2;
        out[base + 1536] = x[base + 1536] + gam * a[3] * li3;
      }
    }
  }
}

// ---------------- launch ----------------
extern "C" void kernel_launch(void* const* d_in, const int* in_sizes, int n_in,
                              void* d_out, int out_size, void* d_ws, size_t ws_size,
                              hipStream_t stream) {
  (void)in_sizes; (void)n_in; (void)out_size; (void)ws_size;
  const float* x  = (const float*)d_in[0];
  const float* Wq = (const float*)d_in[1];
  const float* bq = (const float*)d_in[2];
  const float* Wk = (const float*)d_in[3];
  const float* bk = (const float*)d_in[4];
  const float* gm = (const float*)d_in[5];
  float* out = (float*)d_out;

  char* ws = (char*)d_ws;   // ~68.2 MB
  unsigned short* Qb  = (unsigned short*)(ws);                // 16384*512 bf16
  unsigned short* Kb  = (unsigned short*)(ws + 16777216);     // 16384*512 bf16
  unsigned short* xT  = (unsigned short*)(ws + 33554432);     // 4*512*4096 bf16
  unsigned short* xb  = (unsigned short*)(ws + 50331648);     // 16384*512 bf16
  unsigned short* Wqb = (unsigned short*)(ws + 67108864);     // 512*512 bf16
  unsigned short* Wkb = (unsigned short*)(ws + 67633152);     // 512*512 bf16

  hipFuncSetAttribute((const void*)attn_kernel,
                      hipFuncAttributeMaxDynamicSharedMemorySize, 150288);

  cvt_w<<<512, 256, 0, stream>>>(Wq, Wk, Wqb, Wkb);
  prep_x<<<2048, 256, 0, stream>>>(x, xb, xT);
  proj_gemm<<<dim3(128, 4, 2), 256, 0, stream>>>(xb, Wqb, Wkb, bq, bk, Qb, Kb,
                                                 0.04419417382415922f);
  attn_kernel<<<256, 640, 150288, stream>>>(Qb, Kb, xT, x, gm, out);
}

// Round 8
// 181.573 us; speedup vs baseline: 2.5665x; 2.4377x over previous
//
#include <hip/hip_runtime.h>
#include <hip/hip_bf16.h>
#include <stdint.h>

// LightAttention: out = x + gamma * softmax((x Wq^T)(x Wk^T)^T / sqrt(D)) @ x
// B=4, T=4096, D=512, fp32 in/out.
// R8: attention operands in fp8 e4m3 (Q,K,V,P) to halve L2/L3 traffic —
// R3..R7 showed slot time is pinned by ~32MB/slot of staged K+V traffic
// (9.1 TB/s cache-hierarchy ceiling), all compute pipes <35% busy.

#define B_ 4
#define T_ 4096
#define D_ 512

typedef short short8 __attribute__((ext_vector_type(8)));   // 8 bf16 in 4 VGPRs
typedef float f32x4 __attribute__((ext_vector_type(4)));

__device__ __forceinline__ unsigned short f2bf(float x) {
  union { float f; unsigned u; } v; v.f = x;
  unsigned r = v.u + 0x7fffu + ((v.u >> 16) & 1u);   // RNE
  return (unsigned short)(r >> 16);
}
__device__ __forceinline__ unsigned char f2fp8(float x) {
  return (unsigned char)(__builtin_amdgcn_cvt_pk_fp8_f32(x, x, 0, false) & 0xff);
}
__device__ __forceinline__ float bf2f(unsigned short b) {
  union { unsigned u; float f; } v; v.u = ((unsigned)b) << 16; return v.f;
}

__device__ __forceinline__ void gload_lds16(const void* g, void* l) {
  __builtin_amdgcn_global_load_lds((const __attribute__((address_space(1))) void*)g,
                                   (__attribute__((address_space(3))) void*)l, 16, 0, 0);
}

// ---------------- kernel 1: Wq/Wk fp32 -> bf16 ----------------
__global__ __launch_bounds__(256) void cvt_w(const float* __restrict__ wq,
                                             const float* __restrict__ wk,
                                             unsigned short* __restrict__ oq,
                                             unsigned short* __restrict__ ok) {
  int i = (blockIdx.x * 256 + threadIdx.x) * 4;
  const float* s; unsigned short* d;
  if (i < 262144) { s = wq + i; d = oq + i; }
  else            { s = wk + (i - 262144); d = ok + (i - 262144); }
  float4 v = *(const float4*)s;
  ushort4 h; h.x = f2bf(v.x); h.y = f2bf(v.y); h.z = f2bf(v.z); h.w = f2bf(v.w);
  *(ushort4*)d = h;
}

// ---------------- kernel 2: x -> xb (bf16 row-major) + xV (fp8, tile-contig) --------
// xV layout: [b][tile(64kv)][d(512)][64 t-in-tile] fp8 — each kv-tile is a
// contiguous 32KB block so every cache line fetched in a slot is fully used.
__global__ __launch_bounds__(256) void prep_x(const float* __restrict__ x,
                                              unsigned short* __restrict__ xb,
                                              unsigned char* __restrict__ xV) {
  __shared__ unsigned short ldsT[64][72];
  int wg = blockIdx.x;                 // 2048 = 4 * (4096/64) * (512/64)
  int b = wg >> 9;
  int rem = wg & 511;
  int tt = rem >> 3, dt = rem & 7;
  int t0 = tt * 64, d0 = dt * 64;
  int tid = threadIdx.x;
  int p = tid & 15, rw = tid >> 4;
#pragma unroll
  for (int k = 0; k < 4; ++k) {
    int tr = rw + 16 * k;
    size_t off = ((size_t)(b * 4096 + t0 + tr)) * 512 + d0 + p * 4;
    float4 v = *(const float4*)(x + off);
    ushort4 h; h.x = f2bf(v.x); h.y = f2bf(v.y); h.z = f2bf(v.z); h.w = f2bf(v.w);
    *(ushort4*)(xb + off) = h;
    ldsT[p * 4 + 0][tr] = h.x; ldsT[p * 4 + 1][tr] = h.y;
    ldsT[p * 4 + 2][tr] = h.z; ldsT[p * 4 + 3][tr] = h.w;
  }
  __syncthreads();
#pragma unroll
  for (int k = 0; k < 4; ++k) {
    int dr = rw + 16 * k;
    float f0 = bf2f(ldsT[dr][p * 4 + 0]);
    float f1 = bf2f(ldsT[dr][p * 4 + 1]);
    float f2 = bf2f(ldsT[dr][p * 4 + 2]);
    float f3 = bf2f(ldsT[dr][p * 4 + 3]);
    unsigned pk = (unsigned)__builtin_amdgcn_cvt_pk_fp8_f32(f0, f1, 0, false);
    pk = (unsigned)__builtin_amdgcn_cvt_pk_fp8_f32(f2, f3, (int)pk, true);
    // dest: ((b*64 + tt)*512 + (d0+dr))*64 + p*4
    *(unsigned*)(xV + ((size_t)((b * 64 + tt) * 512 + d0 + dr)) * 64 + p * 4) = pk;
  }
}

// ---------------- kernel 3: Q/K projection GEMM -> fp8 outputs ----------------
// C[m,n] = sum_k xb[m,k]*W[n,k] + bias[n], stored as fp8 e4m3 (1/sqrt(D) is
// applied later inside the softmax exp, so Q is quantized at O(1) magnitude).
__global__ __launch_bounds__(256, 2) void proj_gemm(const unsigned short* __restrict__ A,
                                                    const unsigned short* __restrict__ wq,
                                                    const unsigned short* __restrict__ wk,
                                                    const float* __restrict__ bq,
                                                    const float* __restrict__ bk,
                                                    unsigned char* __restrict__ Qo,
                                                    unsigned char* __restrict__ Ko) {
  __shared__ unsigned short As[2][8192];
  __shared__ unsigned short Bs[2][8192];
  const int tid = threadIdx.x;
  const int mt = blockIdx.x, nt = blockIdx.y, qk = blockIdx.z;
  const unsigned short* W = qk ? wk : wq;
  const float* bias = qk ? bk : bq;
  unsigned char* out = qk ? Ko : Qo;
  const int m0 = mt * 128, n0 = nt * 128;
  const int l = tid & 63, q15 = l & 15, g = l >> 4;
  const int w = tid >> 6, wm = w >> 1, wn = w & 1;

  auto stage = [&](int buf, int k0) {
#pragma unroll
    for (int j = 0; j < 4; ++j) {
      int chunk = j * 256 + tid;
      int row = chunk >> 3, cc = chunk & 7;
      int ccs = cc ^ (row & 7);
      gload_lds16(A + (size_t)(m0 + row) * 512 + k0 + ccs * 8, &As[buf][chunk * 8]);
      gload_lds16(W + (size_t)(n0 + row) * 512 + k0 + ccs * 8, &Bs[buf][chunk * 8]);
    }
  };
  stage(0, 0);
  __syncthreads();

  f32x4 acc[4][4] = {};
  for (int kt = 0; kt < 8; ++kt) {
    int cur = kt & 1;
    if (kt < 7) stage(cur ^ 1, (kt + 1) * 64);
#pragma unroll
    for (int ks = 0; ks < 2; ++ks) {
      short8 av[4], bv[4];
#pragma unroll
      for (int mf = 0; mf < 4; ++mf) {
        int row = 64 * wm + 16 * mf + q15;
        int cb = (ks * 64 + g * 16) ^ ((row & 7) << 4);
        av[mf] = *(const short8*)((const char*)&As[cur][0] + row * 128 + cb);
      }
#pragma unroll
      for (int nf = 0; nf < 4; ++nf) {
        int row = 64 * wn + 16 * nf + q15;
        int cb = (ks * 64 + g * 16) ^ ((row & 7) << 4);
        bv[nf] = *(const short8*)((const char*)&Bs[cur][0] + row * 128 + cb);
      }
#pragma unroll
      for (int mf = 0; mf < 4; ++mf)
#pragma unroll
        for (int nf = 0; nf < 4; ++nf)
          acc[mf][nf] = __builtin_amdgcn_mfma_f32_16x16x32_bf16(av[mf], bv[nf], acc[mf][nf], 0, 0, 0);
    }
    __syncthreads();
  }
#pragma unroll
  for (int nf = 0; nf < 4; ++nf) {
    int n = n0 + 64 * wn + 16 * nf + q15;
    float bv = bias[n];
#pragma unroll
    for (int mf = 0; mf < 4; ++mf) {
      int mbase = m0 + 64 * wm + 16 * mf + 4 * g;
#pragma unroll
      for (int r = 0; r < 4; ++r)
        out[(size_t)(mbase + r) * 512 + n] = f2fp8(acc[mf][nf][r] + bv);
    }
  }
}

// ---------------- kernel 4: fused flash attention + residual (fp8) ----------------
// 768 threads = 12 waves (R5 structure), KV tile = 64, 64 tiles, all fp8 operands:
//   waves 0-3  (QK): wave w owns q 16w..16w+15. Q frags in regs (32 VGPR fp8);
//                    swapped mfma_fp8(K,Q) -> S^T; per-lane online softmax with
//                    1/sqrt(D) folded into exp; writes P(fp8) + scale + flag.
//   waves 4-11 (PV): wave pw owns dout d 64pw..64pw+63, all 64 q; consumes
//                    P/scale of the PREVIOUS tile; stages next K tile via DMA.
// All sync = __syncthreads() (one per slot).
__global__ __launch_bounds__(768, 3) void attn_kernel(const unsigned char* __restrict__ Qb,
                                                      const unsigned char* __restrict__ Kb,
                                                      const unsigned char* __restrict__ xV,
                                                      const float* __restrict__ x,
                                                      const float* __restrict__ gmp,
                                                      float* __restrict__ out) {
  extern __shared__ char smem[];
  // [0, 65536)     : Kbuf 2 x [64 rows][512 B] fp8, XOR-swizzled 16B chunks
  // [65536, 74752) : P    2 x [64 q][72 B] fp8 (64 kv + 8 pad)
  // [74752, 75264) : scale 2 x [64] f32
  // [75264, 75520) : lsum [64] f32
  // [75520, 75536) : flags 2 x [2... 4] u32 (per-QK-wave "scale==1" flag)
  unsigned char* Pl = (unsigned char*)(smem + 65536);
  float* scale_lds = (float*)(smem + 74752);
  float* lsum_lds  = (float*)(smem + 75264);
  unsigned* flags  = (unsigned*)(smem + 75520);

  const int hw = blockIdx.x;
  const int wg = (hw & 7) * 32 + (hw >> 3);   // XCD-chunked swizzle (256 % 8 == 0)
  const int b = wg >> 6, qt = wg & 63;
  const int tid = threadIdx.x;
  const int w = tid >> 6, l = tid & 63, q15 = l & 15, g = l >> 4;
  const float qscale = 0.04419417382415922f;   // 1/sqrt(512)

  const unsigned char* KbB = Kb + (size_t)b * 4096 * 512;
  const unsigned char* xVb = xV + (size_t)b * 64 * 512 * 64;   // [tile][d][64]

  // stage K tile kt (64 rows x 512 B = 2048 x 16B chunks) by the 8 PV waves.
  // LDS row r, 16B-chunk c holds K[r][16*(c ^ (r&7)) ..+16)
  auto stage = [&](int buf, int kt) {
    const unsigned char* src = KbB + (size_t)kt * 64 * 512;
    char* dst = smem + buf * 32768;
    int st = tid - 256;
#pragma unroll
    for (int j = 0; j < 4; ++j) {
      int ch = j * 512 + st;
      int r = ch >> 5, c = ch & 31;
      gload_lds16(src + (size_t)r * 512 + ((c ^ (r & 7)) << 4), dst + ch * 16);
    }
  };

  if (tid >= 256) stage(0, 0);
  __syncthreads();

  if (w < 4) {
    // ================= QK + softmax waves (16 q each) =================
    // Q frags: qf_[ds] = Q[qt*64+16w+q15][32ds+8g .. +8) as 8 fp8
    long qf_[16];
    {
      const unsigned char* Qrow =
          Qb + ((size_t)(b * 4096 + qt * 64 + 16 * w + q15)) * 512 + g * 8;
#pragma unroll
      for (int ds = 0; ds < 16; ++ds) qf_[ds] = *(const long*)(Qrow + ds * 32);
    }
    float mrun = -1e30f, lsum = 0.f;

#pragma unroll 1
    for (int s = 0; s <= 64; ++s) {
      if (s < 64) {
        const int cur = s & 1;
        // QK^T (swapped): S^T[kv][q], frag n covers kv 16n..16n+15
        f32x4 Sacc[4] = {};
        const char* kb = smem + cur * 32768;
        __builtin_amdgcn_s_setprio(1);
#pragma unroll
        for (int ds = 0; ds < 16; ++ds) {
          const int ch = 2 * ds + (g >> 1);
          const int half = (g & 1) << 3;
#pragma unroll
          for (int n = 0; n < 4; ++n) {
            int row = 16 * n + q15;
            long kf = *(const long*)(kb + row * 512 + ((ch ^ (row & 7)) << 4) + half);
            Sacc[n] = __builtin_amdgcn_mfma_f32_16x16x32_fp8_fp8(kf, qf_[ds], Sacc[n], 0, 0, 0);
          }
        }
        __builtin_amdgcn_s_setprio(0);
        // online softmax (raw-score domain; qscale folded into exp):
        // lane owns q = 16w+q15; values kv = 16n + 4g + r
        float pmax = -1e30f;
#pragma unroll
        for (int n = 0; n < 4; ++n)
#pragma unroll
          for (int r = 0; r < 4; ++r) pmax = fmaxf(pmax, Sacc[n][r]);
        pmax = fmaxf(pmax, __shfl_xor(pmax, 16, 64));
        pmax = fmaxf(pmax, __shfl_xor(pmax, 32, 64));
        const float mnew = fmaxf(mrun, pmax);
        const float scl = __expf((mrun - mnew) * qscale);
        float psum = 0.f;
        unsigned char* Pp = Pl + cur * 4608 + (16 * w + q15) * 72 + 4 * g;
#pragma unroll
        for (int n = 0; n < 4; ++n) {
          float p0 = __expf((Sacc[n][0] - mnew) * qscale); psum += p0;
          float p1 = __expf((Sacc[n][1] - mnew) * qscale); psum += p1;
          float p2 = __expf((Sacc[n][2] - mnew) * qscale); psum += p2;
          float p3 = __expf((Sacc[n][3] - mnew) * qscale); psum += p3;
          unsigned pk = (unsigned)__builtin_amdgcn_cvt_pk_fp8_f32(p0, p1, 0, false);
          pk = (unsigned)__builtin_amdgcn_cvt_pk_fp8_f32(p2, p3, (int)pk, true);
          *(unsigned*)(Pp + 16 * n) = pk;
        }
        psum += __shfl_xor(psum, 16, 64);
        psum += __shfl_xor(psum, 32, 64);
        lsum = lsum * scl + psum;
        const bool nochg = (mnew == mrun);
        mrun = mnew;
        if (g == 0) scale_lds[cur * 64 + 16 * w + q15] = scl;
        if (s == 63 && g == 0) lsum_lds[16 * w + q15] = lsum;
        unsigned long long bal = __ballot(nochg ? 1 : 0);
        if (l == 0) flags[cur * 4 + w] = (bal == 0xFFFFFFFFFFFFFFFFull) ? 1u : 0u;
      }
      __syncthreads();
    }
  } else {
    // ================= PV + rescale waves (64 q x 64 d each) =================
    const int pw = w - 4;
    f32x4 Oacc[4][4] = {};

#pragma unroll 1
    for (int s = 0; s <= 64; ++s) {
      if (s < 63) stage((s + 1) & 1, s + 1);
      if (s >= 1) {
        const int tv = s - 1;            // tile consumed this slot
        const int pcur = tv & 1;
        // V frags from tile-contiguous xV: row d = 64pw+16f+q15, k = 32ks+8g
        long vf[4][2];
        const unsigned char* vt = xVb + (size_t)tv * 512 * 64;
#pragma unroll
        for (int f = 0; f < 4; ++f)
#pragma unroll
          for (int ks = 0; ks < 2; ++ks)
            vf[f][ks] = *(const long*)(vt + (size_t)(64 * pw + 16 * f + q15) * 64
                                       + ks * 32 + g * 8);
        uint4 fv = *(const uint4*)&flags[pcur * 4];
        const bool skip = (fv.x & fv.y & fv.z & fv.w) != 0;
        const float* scp = scale_lds + pcur * 64;
        const unsigned char* Pb = Pl + pcur * 4608;
#pragma unroll
        for (int qf = 0; qf < 4; ++qf) {
          const unsigned char* prow = Pb + (16 * qf + q15) * 72 + g * 8;
          long pa0 = *(const long*)(prow);        // k = 8g..8g+7   (kv 0..31)
          long pa1 = *(const long*)(prow + 32);   // k = 32+8g..+7  (kv 32..63)
          if (!skip) {
            float s0 = scp[16 * qf + 4 * g + 0];
            float s1 = scp[16 * qf + 4 * g + 1];
            float s2 = scp[16 * qf + 4 * g + 2];
            float s3 = scp[16 * qf + 4 * g + 3];
#pragma unroll
            for (int f = 0; f < 4; ++f) {
              Oacc[qf][f][0] *= s0; Oacc[qf][f][1] *= s1;
              Oacc[qf][f][2] *= s2; Oacc[qf][f][3] *= s3;
            }
          }
          __builtin_amdgcn_s_setprio(1);
#pragma unroll
          for (int f = 0; f < 4; ++f) {
            f32x4 a = Oacc[qf][f];
            a = __builtin_amdgcn_mfma_f32_16x16x32_fp8_fp8(pa0, vf[f][0], a, 0, 0, 0);
            a = __builtin_amdgcn_mfma_f32_16x16x32_fp8_fp8(pa1, vf[f][1], a, 0, 0, 0);
            Oacc[qf][f] = a;
          }
          __builtin_amdgcn_s_setprio(0);
        }
      }
      __syncthreads();
    }

    // epilogue: PV waves write out
    const float gam = gmp[0];
#pragma unroll
    for (int qf = 0; qf < 4; ++qf) {
      float li0 = 1.f / lsum_lds[16 * qf + 4 * g + 0];
      float li1 = 1.f / lsum_lds[16 * qf + 4 * g + 1];
      float li2 = 1.f / lsum_lds[16 * qf + 4 * g + 2];
      float li3 = 1.f / lsum_lds[16 * qf + 4 * g + 3];
#pragma unroll
      for (int f = 0; f < 4; ++f) {
        int d = 64 * pw + 16 * f + q15;
        size_t base = ((size_t)(b * 4096 + qt * 64 + 16 * qf + 4 * g)) * 512 + d;
        f32x4 a = Oacc[qf][f];
        out[base]        = x[base]        + gam * a[0] * li0;
        out[base + 512]  = x[base + 512]  + gam * a[1] * li1;
        out[base + 1024] = x[base + 1024] + gam * a[2] * li2;
        out[base + 1536] = x[base + 1536] + gam * a[3] * li3;
      }
    }
  }
}

// ---------------- launch ----------------
extern "C" void kernel_launch(void* const* d_in, const int* in_sizes, int n_in,
                              void* d_out, int out_size, void* d_ws, size_t ws_size,
                              hipStream_t stream) {
  (void)in_sizes; (void)n_in; (void)out_size; (void)ws_size;
  const float* x  = (const float*)d_in[0];
  const float* Wq = (const float*)d_in[1];
  const float* bq = (const float*)d_in[2];
  const float* Wk = (const float*)d_in[3];
  const float* bk = (const float*)d_in[4];
  const float* gm = (const float*)d_in[5];
  float* out = (float*)d_out;

  char* ws = (char*)d_ws;
  unsigned char*  Qb  = (unsigned char*)(ws);                 // 16384*512 fp8 = 8 MB
  unsigned char*  Kb  = (unsigned char*)(ws + 8388608);       // 8 MB
  unsigned char*  xV  = (unsigned char*)(ws + 16777216);      // 4*64*512*64 fp8 = 8 MB
  unsigned short* xb  = (unsigned short*)(ws + 25165824);     // 16384*512 bf16 = 16 MB
  unsigned short* Wqb = (unsigned short*)(ws + 41943040);     // 512*512 bf16
  unsigned short* Wkb = (unsigned short*)(ws + 42467328);     // 512*512 bf16

  hipFuncSetAttribute((const void*)attn_kernel,
                      hipFuncAttributeMaxDynamicSharedMemorySize, 75536);

  cvt_w<<<512, 256, 0, stream>>>(Wq, Wk, Wqb, Wkb);
  prep_x<<<2048, 256, 0, stream>>>(x, xb, xV);
  proj_gemm<<<dim3(128, 4, 2), 256, 0, stream>>>(xb, Wqb, Wkb, bq, bk, Qb, Kb);
  attn_kernel<<<256, 768, 75536, stream>>>(Qb, Kb, xV, x, gm, out);
}

// Round 9
// 170.904 us; speedup vs baseline: 2.7267x; 1.0624x over previous
//
#include <hip/hip_runtime.h>
#include <hip/hip_bf16.h>
#include <stdint.h>

// LightAttention: out = x + gamma * softmax((x Wq^T)(x Wk^T)^T / sqrt(D)) @ x
// B=4, T=4096, D=512, fp32 in/out.
// R9: KVBLK 64 -> 128 (slots 64 -> 32) to amortize the measured ~1.56us/slot
// fixed cost (model from R5/R6/R8: slot = 1.56us + chipMB/16.5TB/s).

#define B_ 4
#define T_ 4096
#define D_ 512

typedef short short8 __attribute__((ext_vector_type(8)));   // 8 bf16 in 4 VGPRs
typedef float f32x4 __attribute__((ext_vector_type(4)));

__device__ __forceinline__ unsigned short f2bf(float x) {
  union { float f; unsigned u; } v; v.f = x;
  unsigned r = v.u + 0x7fffu + ((v.u >> 16) & 1u);   // RNE
  return (unsigned short)(r >> 16);
}
__device__ __forceinline__ unsigned char f2fp8(float x) {
  return (unsigned char)(__builtin_amdgcn_cvt_pk_fp8_f32(x, x, 0, false) & 0xff);
}
__device__ __forceinline__ float bf2f(unsigned short b) {
  union { unsigned u; float f; } v; v.u = ((unsigned)b) << 16; return v.f;
}

__device__ __forceinline__ void gload_lds16(const void* g, void* l) {
  __builtin_amdgcn_global_load_lds((const __attribute__((address_space(1))) void*)g,
                                   (__attribute__((address_space(3))) void*)l, 16, 0, 0);
}

// ---------------- kernel 1: Wq/Wk fp32 -> bf16 ----------------
__global__ __launch_bounds__(256) void cvt_w(const float* __restrict__ wq,
                                             const float* __restrict__ wk,
                                             unsigned short* __restrict__ oq,
                                             unsigned short* __restrict__ ok) {
  int i = (blockIdx.x * 256 + threadIdx.x) * 4;
  const float* s; unsigned short* d;
  if (i < 262144) { s = wq + i; d = oq + i; }
  else            { s = wk + (i - 262144); d = ok + (i - 262144); }
  float4 v = *(const float4*)s;
  ushort4 h; h.x = f2bf(v.x); h.y = f2bf(v.y); h.z = f2bf(v.z); h.w = f2bf(v.w);
  *(ushort4*)d = h;
}

// ---------------- kernel 2: x -> xb (bf16 row-major) + xV (fp8, tile-contig) --------
// xV layout: [b][tile(64kv)][d(512)][64 t-in-tile] fp8.
__global__ __launch_bounds__(256) void prep_x(const float* __restrict__ x,
                                              unsigned short* __restrict__ xb,
                                              unsigned char* __restrict__ xV) {
  __shared__ unsigned short ldsT[64][72];
  int wg = blockIdx.x;                 // 2048 = 4 * (4096/64) * (512/64)
  int b = wg >> 9;
  int rem = wg & 511;
  int tt = rem >> 3, dt = rem & 7;
  int t0 = tt * 64, d0 = dt * 64;
  int tid = threadIdx.x;
  int p = tid & 15, rw = tid >> 4;
#pragma unroll
  for (int k = 0; k < 4; ++k) {
    int tr = rw + 16 * k;
    size_t off = ((size_t)(b * 4096 + t0 + tr)) * 512 + d0 + p * 4;
    float4 v = *(const float4*)(x + off);
    ushort4 h; h.x = f2bf(v.x); h.y = f2bf(v.y); h.z = f2bf(v.z); h.w = f2bf(v.w);
    *(ushort4*)(xb + off) = h;
    ldsT[p * 4 + 0][tr] = h.x; ldsT[p * 4 + 1][tr] = h.y;
    ldsT[p * 4 + 2][tr] = h.z; ldsT[p * 4 + 3][tr] = h.w;
  }
  __syncthreads();
#pragma unroll
  for (int k = 0; k < 4; ++k) {
    int dr = rw + 16 * k;
    float f0 = bf2f(ldsT[dr][p * 4 + 0]);
    float f1 = bf2f(ldsT[dr][p * 4 + 1]);
    float f2 = bf2f(ldsT[dr][p * 4 + 2]);
    float f3 = bf2f(ldsT[dr][p * 4 + 3]);
    unsigned pk = (unsigned)__builtin_amdgcn_cvt_pk_fp8_f32(f0, f1, 0, false);
    pk = (unsigned)__builtin_amdgcn_cvt_pk_fp8_f32(f2, f3, (int)pk, true);
    *(unsigned*)(xV + ((size_t)((b * 64 + tt) * 512 + d0 + dr)) * 64 + p * 4) = pk;
  }
}

// ---------------- kernel 3: Q/K projection GEMM -> fp8 outputs ----------------
__global__ __launch_bounds__(256, 2) void proj_gemm(const unsigned short* __restrict__ A,
                                                    const unsigned short* __restrict__ wq,
                                                    const unsigned short* __restrict__ wk,
                                                    const float* __restrict__ bq,
                                                    const float* __restrict__ bk,
                                                    unsigned char* __restrict__ Qo,
                                                    unsigned char* __restrict__ Ko) {
  __shared__ unsigned short As[2][8192];
  __shared__ unsigned short Bs[2][8192];
  const int tid = threadIdx.x;
  const int mt = blockIdx.x, nt = blockIdx.y, qk = blockIdx.z;
  const unsigned short* W = qk ? wk : wq;
  const float* bias = qk ? bk : bq;
  unsigned char* out = qk ? Ko : Qo;
  const int m0 = mt * 128, n0 = nt * 128;
  const int l = tid & 63, q15 = l & 15, g = l >> 4;
  const int w = tid >> 6, wm = w >> 1, wn = w & 1;

  auto stage = [&](int buf, int k0) {
#pragma unroll
    for (int j = 0; j < 4; ++j) {
      int chunk = j * 256 + tid;
      int row = chunk >> 3, cc = chunk & 7;
      int ccs = cc ^ (row & 7);
      gload_lds16(A + (size_t)(m0 + row) * 512 + k0 + ccs * 8, &As[buf][chunk * 8]);
      gload_lds16(W + (size_t)(n0 + row) * 512 + k0 + ccs * 8, &Bs[buf][chunk * 8]);
    }
  };
  stage(0, 0);
  __syncthreads();

  f32x4 acc[4][4] = {};
  for (int kt = 0; kt < 8; ++kt) {
    int cur = kt & 1;
    if (kt < 7) stage(cur ^ 1, (kt + 1) * 64);
#pragma unroll
    for (int ks = 0; ks < 2; ++ks) {
      short8 av[4], bv[4];
#pragma unroll
      for (int mf = 0; mf < 4; ++mf) {
        int row = 64 * wm + 16 * mf + q15;
        int cb = (ks * 64 + g * 16) ^ ((row & 7) << 4);
        av[mf] = *(const short8*)((const char*)&As[cur][0] + row * 128 + cb);
      }
#pragma unroll
      for (int nf = 0; nf < 4; ++nf) {
        int row = 64 * wn + 16 * nf + q15;
        int cb = (ks * 64 + g * 16) ^ ((row & 7) << 4);
        bv[nf] = *(const short8*)((const char*)&Bs[cur][0] + row * 128 + cb);
      }
#pragma unroll
      for (int mf = 0; mf < 4; ++mf)
#pragma unroll
        for (int nf = 0; nf < 4; ++nf)
          acc[mf][nf] = __builtin_amdgcn_mfma_f32_16x16x32_bf16(av[mf], bv[nf], acc[mf][nf], 0, 0, 0);
    }
    __syncthreads();
  }
#pragma unroll
  for (int nf = 0; nf < 4; ++nf) {
    int n = n0 + 64 * wn + 16 * nf + q15;
    float bv = bias[n];
#pragma unroll
    for (int mf = 0; mf < 4; ++mf) {
      int mbase = m0 + 64 * wm + 16 * mf + 4 * g;
#pragma unroll
      for (int r = 0; r < 4; ++r)
        out[(size_t)(mbase + r) * 512 + n] = f2fp8(acc[mf][nf][r] + bv);
    }
  }
}

// ---------------- kernel 4: fused flash attention + residual (fp8, KVBLK=128) ------
// 768 threads = 12 waves, KV tile = 128, 32 tiles:
//   waves 0-3  (QK): wave w owns q 16w..16w+15. Q frags in regs; swapped
//                    mfma_fp8(K,Q) -> S^T (8 kv-frags); per-lane online softmax
//                    (32 values); writes P(fp8) + scale + flag.
//   waves 4-11 (PV): wave pw owns dout d 64pw..64pw+63, all 64 q; consumes
//                    P/scale of the PREVIOUS tile; stages next K tile via DMA.
// All sync = __syncthreads() (one per slot).
__global__ __launch_bounds__(768, 3) void attn_kernel(const unsigned char* __restrict__ Qb,
                                                      const unsigned char* __restrict__ Kb,
                                                      const unsigned char* __restrict__ xV,
                                                      const float* __restrict__ x,
                                                      const float* __restrict__ gmp,
                                                      float* __restrict__ out) {
  extern __shared__ char smem[];
  // [0, 131072)      : Kbuf 2 x [128 rows][512 B] fp8, XOR-swizzled 16B chunks
  // [131072, 149504) : P 2 x [64 q][144 B] fp8 (128 kv + 16 pad; 144 -> 2-way banks)
  // [149504, 150016) : scale 2 x [64] f32
  // [150016, 150272) : lsum [64] f32
  // [150272, 150304) : flags 2 x [4] u32 (per-QK-wave "scale==1" flag)
  unsigned char* Pl = (unsigned char*)(smem + 131072);
  float* scale_lds = (float*)(smem + 149504);
  float* lsum_lds  = (float*)(smem + 150016);
  unsigned* flags  = (unsigned*)(smem + 150272);

  const int hw = blockIdx.x;
  const int wg = (hw & 7) * 32 + (hw >> 3);   // XCD-chunked swizzle (256 % 8 == 0)
  const int b = wg >> 6, qt = wg & 63;
  const int tid = threadIdx.x;
  const int w = tid >> 6, l = tid & 63, q15 = l & 15, g = l >> 4;
  const float qscale = 0.04419417382415922f;   // 1/sqrt(512)

  const unsigned char* KbB = Kb + (size_t)b * 4096 * 512;
  const unsigned char* xVb = xV + (size_t)b * 64 * 512 * 64;   // [tile64][d][64]

  // stage K tile kt (128 rows x 512 B = 4096 x 16B chunks) by the 8 PV waves.
  // LDS row r, 16B-chunk c holds K[r][16*(c ^ (r&7)) ..+16)
  auto stage = [&](int buf, int kt) {
    const unsigned char* src = KbB + (size_t)kt * 128 * 512;
    char* dst = smem + buf * 65536;
    int st = tid - 256;
#pragma unroll
    for (int j = 0; j < 8; ++j) {
      int ch = j * 512 + st;
      int r = ch >> 5, c = ch & 31;
      gload_lds16(src + (size_t)r * 512 + ((c ^ (r & 7)) << 4), dst + ch * 16);
    }
  };

  if (tid >= 256) stage(0, 0);
  __syncthreads();

  if (w < 4) {
    // ================= QK + softmax waves (16 q each) =================
    long qf_[16];
    {
      const unsigned char* Qrow =
          Qb + ((size_t)(b * 4096 + qt * 64 + 16 * w + q15)) * 512 + g * 8;
#pragma unroll
      for (int ds = 0; ds < 16; ++ds) qf_[ds] = *(const long*)(Qrow + ds * 32);
    }
    float mrun = -1e30f, lsum = 0.f;

#pragma unroll 1
    for (int s = 0; s <= 32; ++s) {
      if (s < 32) {
        const int cur = s & 1;
        // QK^T (swapped): S^T[kv][q], frag n covers kv 16n..16n+15 (n=0..7)
        f32x4 Sacc[8] = {};
        const char* kb = smem + cur * 65536;
        __builtin_amdgcn_s_setprio(1);
#pragma unroll
        for (int ds = 0; ds < 16; ++ds) {
          const int ch = 2 * ds + (g >> 1);
          const int half = (g & 1) << 3;
#pragma unroll
          for (int n = 0; n < 8; ++n) {
            int row = 16 * n + q15;
            long kf = *(const long*)(kb + row * 512 + ((ch ^ (row & 7)) << 4) + half);
            Sacc[n] = __builtin_amdgcn_mfma_f32_16x16x32_fp8_fp8(kf, qf_[ds], Sacc[n], 0, 0, 0);
          }
        }
        __builtin_amdgcn_s_setprio(0);
        // online softmax: lane owns q = 16w+q15; values kv = 16n + 4g + r
        float pmax = -1e30f;
#pragma unroll
        for (int n = 0; n < 8; ++n)
#pragma unroll
          for (int r = 0; r < 4; ++r) pmax = fmaxf(pmax, Sacc[n][r]);
        pmax = fmaxf(pmax, __shfl_xor(pmax, 16, 64));
        pmax = fmaxf(pmax, __shfl_xor(pmax, 32, 64));
        const float mnew = fmaxf(mrun, pmax);
        const float scl = __expf((mrun - mnew) * qscale);
        float psum = 0.f;
        unsigned char* Pp = Pl + cur * 9216 + (16 * w + q15) * 144 + 4 * g;
#pragma unroll
        for (int n = 0; n < 8; ++n) {
          float p0 = __expf((Sacc[n][0] - mnew) * qscale); psum += p0;
          float p1 = __expf((Sacc[n][1] - mnew) * qscale); psum += p1;
          float p2 = __expf((Sacc[n][2] - mnew) * qscale); psum += p2;
          float p3 = __expf((Sacc[n][3] - mnew) * qscale); psum += p3;
          unsigned pk = (unsigned)__builtin_amdgcn_cvt_pk_fp8_f32(p0, p1, 0, false);
          pk = (unsigned)__builtin_amdgcn_cvt_pk_fp8_f32(p2, p3, (int)pk, true);
          *(unsigned*)(Pp + 16 * n) = pk;
        }
        psum += __shfl_xor(psum, 16, 64);
        psum += __shfl_xor(psum, 32, 64);
        lsum = lsum * scl + psum;
        const bool nochg = (mnew == mrun);
        mrun = mnew;
        if (g == 0) scale_lds[cur * 64 + 16 * w + q15] = scl;
        if (s == 31 && g == 0) lsum_lds[16 * w + q15] = lsum;
        unsigned long long bal = __ballot(nochg ? 1 : 0);
        if (l == 0) flags[cur * 4 + w] = (bal == 0xFFFFFFFFFFFFFFFFull) ? 1u : 0u;
      }
      __syncthreads();
    }
  } else {
    // ================= PV + rescale waves (64 q x 64 d each) =================
    const int pw = w - 4;
    f32x4 Oacc[4][4] = {};

#pragma unroll 1
    for (int s = 0; s <= 32; ++s) {
      if (s < 31) stage((s + 1) & 1, s + 1);
      if (s >= 1) {
        const int tv = s - 1;            // tile consumed this slot
        const int pcur = tv & 1;
        // V frags from tile-contiguous xV (two 64-kv subtiles per 128 tile):
        // row d = 64pw+16f+q15, k-slice ks covers kv 32ks..+31
        long vf[4][4];
#pragma unroll
        for (int f = 0; f < 4; ++f)
#pragma unroll
          for (int ks = 0; ks < 4; ++ks)
            vf[f][ks] = *(const long*)(xVb + (size_t)(2 * tv + (ks >> 1)) * 32768
                                       + (size_t)(64 * pw + 16 * f + q15) * 64
                                       + ((ks & 1) << 5) + g * 8);
        uint4 fv = *(const uint4*)&flags[pcur * 4];
        const bool skip = (fv.x & fv.y & fv.z & fv.w) != 0;
        const float* scp = scale_lds + pcur * 64;
        const unsigned char* Pb = Pl + pcur * 9216;
#pragma unroll
        for (int qf = 0; qf < 4; ++qf) {
          const unsigned char* prow = Pb + (16 * qf + q15) * 144 + g * 8;
          long pa[4];
#pragma unroll
          for (int ks = 0; ks < 4; ++ks) pa[ks] = *(const long*)(prow + 32 * ks);
          if (!skip) {
            float s0 = scp[16 * qf + 4 * g + 0];
            float s1 = scp[16 * qf + 4 * g + 1];
            float s2 = scp[16 * qf + 4 * g + 2];
            float s3 = scp[16 * qf + 4 * g + 3];
#pragma unroll
            for (int f = 0; f < 4; ++f) {
              Oacc[qf][f][0] *= s0; Oacc[qf][f][1] *= s1;
              Oacc[qf][f][2] *= s2; Oacc[qf][f][3] *= s3;
            }
          }
          __builtin_amdgcn_s_setprio(1);
#pragma unroll
          for (int f = 0; f < 4; ++f) {
            f32x4 a = Oacc[qf][f];
#pragma unroll
            for (int ks = 0; ks < 4; ++ks)
              a = __builtin_amdgcn_mfma_f32_16x16x32_fp8_fp8(pa[ks], vf[f][ks], a, 0, 0, 0);
            Oacc[qf][f] = a;
          }
          __builtin_amdgcn_s_setprio(0);
        }
      }
      __syncthreads();
    }

    // epilogue: PV waves write out
    const float gam = gmp[0];
#pragma unroll
    for (int qf = 0; qf < 4; ++qf) {
      float li0 = 1.f / lsum_lds[16 * qf + 4 * g + 0];
      float li1 = 1.f / lsum_lds[16 * qf + 4 * g + 1];
      float li2 = 1.f / lsum_lds[16 * qf + 4 * g + 2];
      float li3 = 1.f / lsum_lds[16 * qf + 4 * g + 3];
#pragma unroll
      for (int f = 0; f < 4; ++f) {
        int d = 64 * pw + 16 * f + q15;
        size_t base = ((size_t)(b * 4096 + qt * 64 + 16 * qf + 4 * g)) * 512 + d;
        f32x4 a = Oacc[qf][f];
        out[base]        = x[base]        + gam * a[0] * li0;
        out[base + 512]  = x[base + 512]  + gam * a[1] * li1;
        out[base + 1024] = x[base + 1024] + gam * a[2] * li2;
        out[base + 1536] = x[base + 1536] + gam * a[3] * li3;
      }
    }
  }
}

// ---------------- launch ----------------
extern "C" void kernel_launch(void* const* d_in, const int* in_sizes, int n_in,
                              void* d_out, int out_size, void* d_ws, size_t ws_size,
                              hipStream_t stream) {
  (void)in_sizes; (void)n_in; (void)out_size; (void)ws_size;
  const float* x  = (const float*)d_in[0];
  const float* Wq = (const float*)d_in[1];
  const float* bq = (const float*)d_in[2];
  const float* Wk = (const float*)d_in[3];
  const float* bk = (const float*)d_in[4];
  const float* gm = (const float*)d_in[5];
  float* out = (float*)d_out;

  char* ws = (char*)d_ws;
  unsigned char*  Qb  = (unsigned char*)(ws);                 // 16384*512 fp8 = 8 MB
  unsigned char*  Kb  = (unsigned char*)(ws + 8388608);       // 8 MB
  unsigned char*  xV  = (unsigned char*)(ws + 16777216);      // 4*64*512*64 fp8 = 8 MB
  unsigned short* xb  = (unsigned short*)(ws + 25165824);     // 16384*512 bf16 = 16 MB
  unsigned short* Wqb = (unsigned short*)(ws + 41943040);     // 512*512 bf16
  unsigned short* Wkb = (unsigned short*)(ws + 42467328);     // 512*512 bf16

  hipFuncSetAttribute((const void*)attn_kernel,
                      hipFuncAttributeMaxDynamicSharedMemorySize, 150304);

  cvt_w<<<512, 256, 0, stream>>>(Wq, Wk, Wqb, Wkb);
  prep_x<<<2048, 256, 0, stream>>>(x, xb, xV);
  proj_gemm<<<dim3(128, 4, 2), 256, 0, stream>>>(xb, Wqb, Wkb, bq, bk, Qb, Kb);
  attn_kernel<<<256, 768, 150304, stream>>>(Qb, Kb, xV, x, gm, out);
}